// Round 7
// baseline (216.306 us; speedup 1.0000x reference)
//
#include <hip/hip_runtime.h>
#include <hip/hip_fp16.h>
#include <math.h>
#include <stdint.h>

#define D 128
typedef __attribute__((ext_vector_type(8))) _Float16 f16x8;
typedef __attribute__((ext_vector_type(4))) float f32x4;
typedef unsigned short ushort_t;

__device__ inline unsigned pack_f16(float a, float b) {
    __half2 h = __floats2half2_rn(a, b);
    return __builtin_bit_cast(unsigned, h);
}
__device__ inline ushort_t f16_of(float f) {
    __half h = __float2half_rn(f);
    return __builtin_bit_cast(ushort_t, h);
}
__device__ inline __half2 hmax2(__half2 a, __half2 b) {
    unsigned ua = __builtin_bit_cast(unsigned, a);
    unsigned ub = __builtin_bit_cast(unsigned, b);
    unsigned r;
    asm("v_pk_max_f16 %0, %1, %2" : "=v"(r) : "v"(ua), "v"(ub));
    return __builtin_bit_cast(__half2, r);
}

struct __align__(16) H8 { __half2 h[4]; };

// ---------------- edge pack + histogram (reads 24B/edge once) ----------------
// rec = sub:16 | (rel*64 + r_idx):15
__global__ void pack_hist(const int* __restrict__ edges, unsigned* __restrict__ rec,
                          int* __restrict__ obj, int* __restrict__ count, int E) {
    const int i = blockIdx.x * blockDim.x + threadIdx.x;
    const int stride = gridDim.x * blockDim.x;
    const uint2* e2 = (const uint2*)edges;
    for (int e = i; e < E; e += stride) {
        const unsigned r_idx = e2[e * 3 + 0].x;
        const unsigned rel   = e2[e * 3 + 1].x;
        const uint2 so       = e2[e * 3 + 2];     // .x=sub .y=obj
        rec[e] = so.x | ((rel * 64u + r_idx) << 16);
        obj[e] = (int)so.y;
        atomicAdd(&count[so.y], 1);
    }
}

// ---------------- 2-phase exclusive scan ----------------
__global__ void scan_partial(const int* __restrict__ count, int* __restrict__ bsum, int M) {
    __shared__ int wsum[16];
    const int t = threadIdx.x, lane = t & 63, w = t >> 6;
    const int i = blockIdx.x * 1024 + t;
    int v = (i < M) ? count[i] : 0;
    #pragma unroll
    for (int off = 32; off > 0; off >>= 1) v += __shfl_xor(v, off, 64);
    if (lane == 0) wsum[w] = v;
    __syncthreads();
    if (w == 0) {
        int s = (lane < 16) ? wsum[lane] : 0;
        #pragma unroll
        for (int off = 8; off > 0; off >>= 1) s += __shfl_xor(s, off, 16);
        if (lane == 0) bsum[blockIdx.x] = s;
    }
}

__global__ void scan_final(const int* __restrict__ count, const int* __restrict__ bsum,
                           int* __restrict__ start, int* __restrict__ cursor, int M, int G) {
    __shared__ int wsum[16];
    __shared__ int sboff;
    const int t = threadIdx.x, lane = t & 63, w = t >> 6;
    const int i = blockIdx.x * 1024 + t;
    const int v = (i < M) ? count[i] : 0;
    if (w == 0) {
        int bv = (lane < G) ? bsum[lane] : 0;
        int bx = bv;
        #pragma unroll
        for (int off = 1; off < 64; off <<= 1) {
            int y = __shfl_up(bx, off, 64);
            if (lane >= off) bx += y;
        }
        if (lane == (blockIdx.x & 63)) sboff = bx - bv;
    }
    int x = v;
    #pragma unroll
    for (int off = 1; off < 64; off <<= 1) {
        int y = __shfl_up(x, off, 64);
        if (lane >= off) x += y;
    }
    if (lane == 63) wsum[w] = x;
    __syncthreads();
    if (w == 0) {
        int s = (lane < 16) ? wsum[lane] : 0;
        int xs = s;
        #pragma unroll
        for (int off = 1; off < 16; off <<= 1) {
            int y = __shfl_up(xs, off, 64);
            if (lane >= off) xs += y;
        }
        if (lane < 16) wsum[lane] = xs - s;
    }
    __syncthreads();
    const int excl = x - v + wsum[w] + sboff;
    if (i < M) {
        start[i] = excl;
        cursor[i] = excl;
        if (i == M - 1) start[M] = excl + v;
    }
}

// ---------------- scatter packed recs into CSR order ----------------
__global__ void scatter2(const unsigned* __restrict__ rec, const int* __restrict__ obj,
                         int* __restrict__ cursor, unsigned* __restrict__ sorted, int E) {
    const int i = blockIdx.x * blockDim.x + threadIdx.x;
    const int stride = gridDim.x * blockDim.x;
    for (int e = i; e < E; e += stride) {
        const int pos = atomicAdd(&cursor[obj[e]], 1);
        sorted[pos] = rec[e];
    }
}

// ---------------- W -> W^T fp16 prep (4 matrices, 1 block each) ----------------
__global__ void prep_wt(const float* __restrict__ W0, const float* __restrict__ W1,
                        const float* __restrict__ W2, const float* __restrict__ W3,
                        ushort_t* __restrict__ Wt4) {
    __shared__ ushort_t sT[D * D];
    const float* src = blockIdx.x == 0 ? W0 : blockIdx.x == 1 ? W1 : blockIdx.x == 2 ? W2 : W3;
    ushort_t* dst = Wt4 + (size_t)blockIdx.x * (D * D);
    const int t = threadIdx.x;
    for (int i = t; i < D * D; i += 256) {
        const int k = i >> 7, col = i & 127;
        sT[col * D + k] = f16_of(src[i]);
    }
    __syncthreads();
    const uint4* s8 = (const uint4*)sT;
    uint4* d8 = (uint4*)dst;
    for (int i = t; i < D * D / 8; i += 256) d8[i] = s8[i];
}

// ---------------- hrq[rel*64+ridx] = hr_proj[rel] + qr_proj[ridx] (fp16) ----------------
__global__ void hrq_prep(const __half* __restrict__ hrcombo, const __half* __restrict__ qrb,
                         __half* __restrict__ hrq, int R) {
    const int total = R * 64 * 64;   // __half2 elements
    const int i0 = blockIdx.x * blockDim.x + threadIdx.x;
    const int stride = gridDim.x * blockDim.x;
    const __half2* hr2 = (const __half2*)hrcombo;
    const __half2* qr2 = (const __half2*)qrb;
    __half2* out2 = (__half2*)hrq;
    for (int i = i0; i < total; i += stride) {
        const int row = i >> 6, h = i & 63;
        const int rel = row >> 6, ridx = row & 63;
        out2[(size_t)row * 64 + h] = __hadd2(hr2[(size_t)rel * 128 + 64 + h],
                                             qr2[(size_t)ridx * 64 + h]);
    }
}

// ---------------- MFMA (fp16) 128x128 projection: Y = relu?(X[rowidx?] @ W + bias) -------
// MODE 1: fp16 combo out ([0:128]=f16(X row), [128:256]=proj). MODE 2: fp16 proj out only.
template<int MODE>
__global__ __launch_bounds__(256, 3)
void gemm_t(const float* __restrict__ X, const ushort_t* __restrict__ Wt,  // fp16 [col][k]
            const float* __restrict__ bias, const int* __restrict__ rowidx,
            void* __restrict__ Yv, int M, int do_relu) {
    __shared__ ushort_t sW[D * D];   // 32 KB, XOR-swizzled
    __shared__ ushort_t sX[64 * D];  // 16 KB, XOR-swizzled
    const int t = threadIdx.x;
    {
        const uint4* src = (const uint4*)Wt;
        for (int s = t; s < 2048; s += 256) {
            const int col = s >> 4;
            const int off = (s & 15) * 16;
            *(uint4*)((char*)sW + col * 256 + (off ^ ((col & 7) << 4))) = src[s];
        }
    }
    const int wave = t >> 6, lane = t & 63;
    const int l15 = lane & 15, lg = lane >> 4;
    __syncthreads();
    for (int r0 = blockIdx.x * 64; r0 < M; r0 += gridDim.x * 64) {
        {
            const int row = t >> 2, q = t & 3;
            const int gr = r0 + row;
            if (gr < M) {
                const int src = rowidx ? rowidx[gr] : gr;
                const float* xp = X + (size_t)src * D + q * 32;
                #pragma unroll
                for (int s = 0; s < 4; ++s) {
                    const float4 v0 = *(const float4*)(xp + s * 8);
                    const float4 v1 = *(const float4*)(xp + s * 8 + 4);
                    uint4 pk;
                    pk.x = pack_f16(v0.x, v0.y); pk.y = pack_f16(v0.z, v0.w);
                    pk.z = pack_f16(v1.x, v1.y); pk.w = pack_f16(v1.z, v1.w);
                    const int off = q * 64 + s * 16;
                    *(uint4*)((char*)sX + row * 256 + (off ^ ((row & 7) << 4))) = pk;
                    if (MODE == 1)
                        *(uint4*)((ushort_t*)Yv + (size_t)gr * 256 + q * 32 + s * 8) = pk;
                }
            }
        }
        __syncthreads();
        f32x4 acc[8];
        #pragma unroll
        for (int ct = 0; ct < 8; ++ct) acc[ct] = (f32x4){0.f, 0.f, 0.f, 0.f};
        #pragma unroll
        for (int kc = 0; kc < 4; ++kc) {
            const int koff = kc * 64 + lg * 16;
            const int arow = wave * 16 + l15;
            const f16x8 afrag = *(const f16x8*)((char*)sX + arow * 256 + (koff ^ ((arow & 7) << 4)));
            #pragma unroll
            for (int ct = 0; ct < 8; ++ct) {
                const int col = ct * 16 + l15;
                const f16x8 bfrag = *(const f16x8*)((char*)sW + col * 256 + (koff ^ ((col & 7) << 4)));
                acc[ct] = __builtin_amdgcn_mfma_f32_16x16x32_f16(afrag, bfrag, acc[ct], 0, 0, 0);
            }
        }
        __syncthreads();
        #pragma unroll
        for (int q2 = 0; q2 < 4; ++q2) {
            const int gr2 = r0 + wave * 16 + lg * 4 + q2;
            if (gr2 < M) {
                #pragma unroll
                for (int ct = 0; ct < 8; ++ct) {
                    const int col = ct * 16 + l15;
                    float v = acc[ct][q2];
                    if (bias) v += bias[col];
                    if (do_relu) v = fmaxf(v, 0.f);
                    if (MODE == 1) ((ushort_t*)Yv)[(size_t)gr2 * 256 + 128 + col] = f16_of(v);
                    else           ((ushort_t*)Yv)[(size_t)gr2 * 128 + col] = f16_of(v);
                }
            }
        }
    }
}

// ---------------- fused: per-node aggregation -> LDS fp16 tile -> MFMA @ Wh -> relu out --
__global__ __launch_bounds__(256, 3)
void agg_gemm(const unsigned* __restrict__ sorted, const int* __restrict__ start,
              const __half* __restrict__ combo,    // [N][256]: hidden | hs_proj
              const __half* __restrict__ hrcombo,  // [R][256]: rela | hr_proj
              const __half* __restrict__ hrq,      // [R*64][128]: hr_proj+qr_proj
              const float* __restrict__ Wa,
              const ushort_t* __restrict__ WhT,    // fp16 [col][k]
              float* __restrict__ out, int N) {
    __shared__ ushort_t sW[D * D];   // 32 KB, XOR-swizzled
    __shared__ ushort_t sA[64 * D];  // 16 KB, XOR-swizzled agg tile
    const int t = threadIdx.x;
    {
        const uint4* src = (const uint4*)WhT;
        for (int s = t; s < 2048; s += 256) {
            const int col = s >> 4;
            const int off = (s & 15) * 16;
            *(uint4*)((char*)sW + col * 256 + (off ^ ((col & 7) << 4))) = src[s];
        }
    }
    const int wave = t >> 6, lane = t & 63;
    const int grp = lane >> 4, sl = lane & 15;
    const int c = sl * 8;
    __half2 wah[4];
    {
        const float4 w0 = *(const float4*)(Wa + c);
        const float4 w1 = *(const float4*)(Wa + c + 4);
        wah[0] = __floats2half2_rn(w0.x, w0.y);
        wah[1] = __floats2half2_rn(w0.z, w0.w);
        wah[2] = __floats2half2_rn(w1.x, w1.y);
        wah[3] = __floats2half2_rn(w1.z, w1.w);
    }
    const __half2 zero2 = __floats2half2_rn(0.f, 0.f);
    __syncthreads();
    for (int r0 = blockIdx.x * 64; r0 < N; r0 += gridDim.x * 64) {
        // ---- aggregation phase: wave handles 16 nodes, 4 edge slots each ----
        for (int i = 0; i < 16; ++i) {
            const int n = r0 + wave * 16 + i;
            float acc[8] = {0.f, 0.f, 0.f, 0.f, 0.f, 0.f, 0.f, 0.f};
            if (n < N) {
                const int e0 = start[n], e1 = start[n + 1];
                for (int e = e0 + grp; e < e1; e += 4) {
                    const unsigned rec = sorted[e];
                    const int sub  = rec & 0xFFFF;
                    const int pair = rec >> 16;
                    const H8 uhid = *(const H8*)(combo + (size_t)sub * 256 + c);
                    const H8 uhsp = *(const H8*)(combo + (size_t)sub * 256 + 128 + c);
                    const H8 uhrq = *(const H8*)(hrq + (size_t)pair * 128 + c);
                    const H8 uhre = *(const H8*)(hrcombo + (size_t)(pair >> 6) * 256 + c);
                    __half2 d2 = zero2;
                    #pragma unroll
                    for (int j = 0; j < 4; ++j) {
                        const __half2 p = hmax2(__hadd2(uhsp.h[j], uhrq.h[j]), zero2);
                        d2 = __hfma2(p, wah[j], d2);
                    }
                    float part = __low2float(d2) + __high2float(d2);
                    #pragma unroll
                    for (int off = 8; off > 0; off >>= 1) part += __shfl_xor(part, off, 64);
                    const float alpha = 1.f / (1.f + __expf(-part));
                    #pragma unroll
                    for (int j = 0; j < 4; ++j) {
                        const __half2 m = __hadd2(uhid.h[j], uhre.h[j]);
                        acc[j * 2]     = fmaf(__low2float(m),  alpha, acc[j * 2]);
                        acc[j * 2 + 1] = fmaf(__high2float(m), alpha, acc[j * 2 + 1]);
                    }
                }
            }
            #pragma unroll
            for (int j = 0; j < 8; ++j) {
                acc[j] += __shfl_xor(acc[j], 16, 64);
                acc[j] += __shfl_xor(acc[j], 32, 64);
            }
            if (grp == 0) {   // write full row (zeros for n>=N) into swizzled LDS tile
                uint4 pk;
                pk.x = pack_f16(acc[0], acc[1]); pk.y = pack_f16(acc[2], acc[3]);
                pk.z = pack_f16(acc[4], acc[5]); pk.w = pack_f16(acc[6], acc[7]);
                const int row = wave * 16 + i;
                const int off = sl * 16;
                *(uint4*)((char*)sA + row * 256 + (off ^ ((row & 7) << 4))) = pk;
            }
        }
        __syncthreads();
        // ---- MFMA phase: out[r0..r0+64) = relu(sA @ Wh) ----
        f32x4 oacc[8];
        #pragma unroll
        for (int ct = 0; ct < 8; ++ct) oacc[ct] = (f32x4){0.f, 0.f, 0.f, 0.f};
        #pragma unroll
        for (int kc = 0; kc < 4; ++kc) {
            const int koff = kc * 64 + grp * 16;
            const int arow = wave * 16 + sl;
            const f16x8 afrag = *(const f16x8*)((char*)sA + arow * 256 + (koff ^ ((arow & 7) << 4)));
            #pragma unroll
            for (int ct = 0; ct < 8; ++ct) {
                const int col = ct * 16 + sl;
                const f16x8 bfrag = *(const f16x8*)((char*)sW + col * 256 + (koff ^ ((col & 7) << 4)));
                oacc[ct] = __builtin_amdgcn_mfma_f32_16x16x32_f16(afrag, bfrag, oacc[ct], 0, 0, 0);
            }
        }
        #pragma unroll
        for (int q2 = 0; q2 < 4; ++q2) {
            const int gr2 = r0 + wave * 16 + grp * 4 + q2;
            if (gr2 < N) {
                #pragma unroll
                for (int ct = 0; ct < 8; ++ct)
                    out[(size_t)gr2 * D + ct * 16 + sl] = fmaxf(oacc[ct][q2], 0.f);
            }
        }
        __syncthreads();   // sA stable until here; next iteration restages
    }
}

extern "C" void kernel_launch(void* const* d_in, const int* in_sizes, int n_in,
                              void* d_out, int out_size, void* d_ws, size_t ws_size,
                              hipStream_t stream) {
    const int*   q_rel  = (const int*)d_in[0];
    const float* hidden = (const float*)d_in[1];
    const int*   edges  = (const int*)d_in[2];
    const float* rela   = (const float*)d_in[3];
    const float* Ws     = (const float*)d_in[4];
    const float* Wr     = (const float*)d_in[5];
    const float* Wqr_w  = (const float*)d_in[6];
    const float* Wqr_b  = (const float*)d_in[7];
    const float* Wa     = (const float*)d_in[8];
    const float* Wh     = (const float*)d_in[9];

    const int B = in_sizes[0];
    const int N = in_sizes[1] / D;
    const int E = in_sizes[2] / 6;
    const int R = in_sizes[3] / D;

    ushort_t* combo   = (ushort_t*)d_ws;                 // N*256 fp16
    ushort_t* hrcombo = combo + (size_t)N * 256;         // R*256 fp16
    ushort_t* qrb     = hrcombo + (size_t)R * 256;       // B*128 fp16
    ushort_t* Wt4     = qrb + (size_t)B * 128;           // 4*128*128 fp16
    ushort_t* hrq     = Wt4 + 4 * D * D;                 // R*64*128 fp16
    int* count  = (int*)(hrq + (size_t)R * 64 * 128);    // N
    int* bsum   = count + N;                             // 64
    int* start  = bsum + 64;                             // N+1
    int* cursor = start + N + 1;                         // N
    unsigned* rec    = (unsigned*)(cursor + N);          // E
    int*      obj    = (int*)(rec + E);                  // E
    unsigned* sorted = (unsigned*)(obj + E);             // E

    // CSR build
    (void)hipMemsetAsync(count, 0, (size_t)N * sizeof(int), stream);
    pack_hist<<<1024, 256, 0, stream>>>(edges, rec, obj, count, E);
    const int G = (N + 1023) / 1024;
    scan_partial<<<G, 1024, 0, stream>>>(count, bsum, N);
    scan_final<<<G, 1024, 0, stream>>>(count, bsum, start, cursor, N, G);
    scatter2<<<1024, 256, 0, stream>>>(rec, obj, cursor, sorted, E);

    // weight prep + MFMA projections (fused fp16 combo production)
    prep_wt<<<4, 256, 0, stream>>>(Ws, Wr, Wqr_w, Wh, Wt4);
    const int TB = (N + 63) / 64;
    gemm_t<1><<<TB, 256, 0, stream>>>(hidden, Wt4, nullptr, nullptr, combo, N, 0);
    gemm_t<1><<<(R + 63) / 64, 256, 0, stream>>>(rela, Wt4 + D * D, nullptr, nullptr, hrcombo, R, 0);
    gemm_t<2><<<(B + 63) / 64, 256, 0, stream>>>(rela, Wt4 + 2 * D * D, Wqr_b, q_rel, qrb, B, 0);
    hrq_prep<<<2048, 256, 0, stream>>>((const __half*)hrcombo, (const __half*)qrb,
                                       (__half*)hrq, R);

    // fused aggregation + final GEMM -> relu -> d_out
    agg_gemm<<<TB, 256, 0, stream>>>(sorted, start, (const __half*)combo,
                                     (const __half*)hrcombo, (const __half*)hrq, Wa,
                                     Wt4 + 3 * D * D, (float*)d_out, N);
}

// Round 8
// 160.680 us; speedup vs baseline: 1.3462x; 1.3462x over previous
//
#include <hip/hip_runtime.h>
#include <hip/hip_fp16.h>
#include <math.h>
#include <stdint.h>

#define D 128
typedef __attribute__((ext_vector_type(8))) _Float16 f16x8;
typedef __attribute__((ext_vector_type(4))) float f32x4;
typedef unsigned short ushort_t;

__device__ inline unsigned pack_f16(float a, float b) {
    __half2 h = __floats2half2_rn(a, b);
    return __builtin_bit_cast(unsigned, h);
}
__device__ inline ushort_t f16_of(float f) {
    __half h = __float2half_rn(f);
    return __builtin_bit_cast(ushort_t, h);
}
__device__ inline __half2 hmax2(__half2 a, __half2 b) {
    unsigned ua = __builtin_bit_cast(unsigned, a);
    unsigned ub = __builtin_bit_cast(unsigned, b);
    unsigned r;
    asm("v_pk_max_f16 %0, %1, %2" : "=v"(r) : "v"(ua), "v"(ub));
    return __builtin_bit_cast(__half2, r);
}

struct __align__(16) H8 { __half2 h[4]; };

// ---------------- edge pack + histogram (reads 24B/edge once) ----------------
// rec = sub:16 | rel:9 | r_idx:7
__global__ void pack_hist(const int* __restrict__ edges, unsigned* __restrict__ rec,
                          int* __restrict__ obj, int* __restrict__ count, int E) {
    const int i = blockIdx.x * blockDim.x + threadIdx.x;
    const int stride = gridDim.x * blockDim.x;
    const uint2* e2 = (const uint2*)edges;
    for (int e = i; e < E; e += stride) {
        const unsigned r_idx = e2[e * 3 + 0].x;
        const unsigned rel   = e2[e * 3 + 1].x;
        const uint2 so       = e2[e * 3 + 2];     // .x=sub .y=obj
        rec[e] = so.x | (rel << 16) | (r_idx << 25);
        obj[e] = (int)so.y;
        atomicAdd(&count[so.y], 1);
    }
}

// ---------------- 2-phase exclusive scan ----------------
__global__ void scan_partial(const int* __restrict__ count, int* __restrict__ bsum, int M) {
    __shared__ int wsum[16];
    const int t = threadIdx.x, lane = t & 63, w = t >> 6;
    const int i = blockIdx.x * 1024 + t;
    int v = (i < M) ? count[i] : 0;
    #pragma unroll
    for (int off = 32; off > 0; off >>= 1) v += __shfl_xor(v, off, 64);
    if (lane == 0) wsum[w] = v;
    __syncthreads();
    if (w == 0) {
        int s = (lane < 16) ? wsum[lane] : 0;
        #pragma unroll
        for (int off = 8; off > 0; off >>= 1) s += __shfl_xor(s, off, 16);
        if (lane == 0) bsum[blockIdx.x] = s;
    }
}

__global__ void scan_final(const int* __restrict__ count, const int* __restrict__ bsum,
                           int* __restrict__ start, int* __restrict__ cursor, int M, int G) {
    __shared__ int wsum[16];
    __shared__ int sboff;
    const int t = threadIdx.x, lane = t & 63, w = t >> 6;
    const int i = blockIdx.x * 1024 + t;
    const int v = (i < M) ? count[i] : 0;
    if (w == 0) {
        int bv = (lane < G) ? bsum[lane] : 0;
        int bx = bv;
        #pragma unroll
        for (int off = 1; off < 64; off <<= 1) {
            int y = __shfl_up(bx, off, 64);
            if (lane >= off) bx += y;
        }
        if (lane == (blockIdx.x & 63)) sboff = bx - bv;
    }
    int x = v;
    #pragma unroll
    for (int off = 1; off < 64; off <<= 1) {
        int y = __shfl_up(x, off, 64);
        if (lane >= off) x += y;
    }
    if (lane == 63) wsum[w] = x;
    __syncthreads();
    if (w == 0) {
        int s = (lane < 16) ? wsum[lane] : 0;
        int xs = s;
        #pragma unroll
        for (int off = 1; off < 16; off <<= 1) {
            int y = __shfl_up(xs, off, 64);
            if (lane >= off) xs += y;
        }
        if (lane < 16) wsum[lane] = xs - s;
    }
    __syncthreads();
    const int excl = x - v + wsum[w] + sboff;
    if (i < M) {
        start[i] = excl;
        cursor[i] = excl;
        if (i == M - 1) start[M] = excl + v;
    }
}

// ---------------- scatter packed recs into CSR order ----------------
__global__ void scatter2(const unsigned* __restrict__ rec, const int* __restrict__ obj,
                         int* __restrict__ cursor, unsigned* __restrict__ sorted, int E) {
    const int i = blockIdx.x * blockDim.x + threadIdx.x;
    const int stride = gridDim.x * blockDim.x;
    for (int e = i; e < E; e += stride) {
        const int pos = atomicAdd(&cursor[obj[e]], 1);
        sorted[pos] = rec[e];
    }
}

// ---------------- W -> W^T fp16 prep (4 matrices, 1 block each) ----------------
__global__ void prep_wt(const float* __restrict__ W0, const float* __restrict__ W1,
                        const float* __restrict__ W2, const float* __restrict__ W3,
                        ushort_t* __restrict__ Wt4) {
    __shared__ ushort_t sT[D * D];
    const float* src = blockIdx.x == 0 ? W0 : blockIdx.x == 1 ? W1 : blockIdx.x == 2 ? W2 : W3;
    ushort_t* dst = Wt4 + (size_t)blockIdx.x * (D * D);
    const int t = threadIdx.x;
    for (int i = t; i < D * D; i += 256) {
        const int k = i >> 7, col = i & 127;
        sT[col * D + k] = f16_of(src[i]);
    }
    __syncthreads();
    const uint4* s8 = (const uint4*)sT;
    uint4* d8 = (uint4*)dst;
    for (int i = t; i < D * D / 8; i += 256) d8[i] = s8[i];
}

// ---------------- MFMA (fp16) 128x128 projection: Y = relu?(X[rowidx?] @ W + bias) -------
// MODE 1: f32 in, fp16 combo out ([0:128]=f16(X row), [128:256]=proj).
// MODE 2: f32 in, fp16 proj out only.
// MODE 3: fp16 in, f32 out (+relu) — final pass, reads Xh.
template<int MODE>
__global__ __launch_bounds__(256, 3)
void gemm_t(const float* __restrict__ X, const ushort_t* __restrict__ Xh,
            const ushort_t* __restrict__ Wt,  // fp16 [col][k]
            const float* __restrict__ bias, const int* __restrict__ rowidx,
            void* __restrict__ Yv, int M, int do_relu) {
    __shared__ ushort_t sW[D * D];   // 32 KB, XOR-swizzled
    __shared__ ushort_t sX[64 * D];  // 16 KB, XOR-swizzled
    const int t = threadIdx.x;
    {
        const uint4* src = (const uint4*)Wt;
        for (int s = t; s < 2048; s += 256) {
            const int col = s >> 4;
            const int off = (s & 15) * 16;
            *(uint4*)((char*)sW + col * 256 + (off ^ ((col & 7) << 4))) = src[s];
        }
    }
    const int wave = t >> 6, lane = t & 63;
    const int l15 = lane & 15, lg = lane >> 4;
    __syncthreads();
    for (int r0 = blockIdx.x * 64; r0 < M; r0 += gridDim.x * 64) {
        if (MODE == 3) {   // fp16 input staging: 64 rows x 16 uint4
            for (int s = t; s < 1024; s += 256) {
                const int row = s >> 4;
                const int gr = r0 + row;
                if (gr < M) {
                    const uint4 pk = *(const uint4*)(Xh + (size_t)gr * D + (s & 15) * 8);
                    const int off = (s & 15) * 16;
                    *(uint4*)((char*)sX + row * 256 + (off ^ ((row & 7) << 4))) = pk;
                }
            }
        } else {           // f32 input staging with fp16 conversion
            const int row = t >> 2, q = t & 3;
            const int gr = r0 + row;
            if (gr < M) {
                const int src = rowidx ? rowidx[gr] : gr;
                const float* xp = X + (size_t)src * D + q * 32;
                #pragma unroll
                for (int s = 0; s < 4; ++s) {
                    const float4 v0 = *(const float4*)(xp + s * 8);
                    const float4 v1 = *(const float4*)(xp + s * 8 + 4);
                    uint4 pk;
                    pk.x = pack_f16(v0.x, v0.y); pk.y = pack_f16(v0.z, v0.w);
                    pk.z = pack_f16(v1.x, v1.y); pk.w = pack_f16(v1.z, v1.w);
                    const int off = q * 64 + s * 16;
                    *(uint4*)((char*)sX + row * 256 + (off ^ ((row & 7) << 4))) = pk;
                    if (MODE == 1)
                        *(uint4*)((ushort_t*)Yv + (size_t)gr * 256 + q * 32 + s * 8) = pk;
                }
            }
        }
        __syncthreads();
        f32x4 acc[8];
        #pragma unroll
        for (int ct = 0; ct < 8; ++ct) acc[ct] = (f32x4){0.f, 0.f, 0.f, 0.f};
        #pragma unroll
        for (int kc = 0; kc < 4; ++kc) {
            const int koff = kc * 64 + lg * 16;
            const int arow = wave * 16 + l15;
            const f16x8 afrag = *(const f16x8*)((char*)sX + arow * 256 + (koff ^ ((arow & 7) << 4)));
            #pragma unroll
            for (int ct = 0; ct < 8; ++ct) {
                const int col = ct * 16 + l15;
                const f16x8 bfrag = *(const f16x8*)((char*)sW + col * 256 + (koff ^ ((col & 7) << 4)));
                acc[ct] = __builtin_amdgcn_mfma_f32_16x16x32_f16(afrag, bfrag, acc[ct], 0, 0, 0);
            }
        }
        __syncthreads();
        #pragma unroll
        for (int q2 = 0; q2 < 4; ++q2) {
            const int gr2 = r0 + wave * 16 + lg * 4 + q2;
            if (gr2 < M) {
                #pragma unroll
                for (int ct = 0; ct < 8; ++ct) {
                    const int col = ct * 16 + l15;
                    float v = acc[ct][q2];
                    if (bias) v += bias[col];
                    if (do_relu) v = fmaxf(v, 0.f);
                    if (MODE == 1)      ((ushort_t*)Yv)[(size_t)gr2 * 256 + 128 + col] = f16_of(v);
                    else if (MODE == 2) ((ushort_t*)Yv)[(size_t)gr2 * 128 + col] = f16_of(v);
                    else                ((float*)Yv)[(size_t)gr2 * D + col] = v;
                }
            }
        }
    }
}

// ---------------- per-node gather aggregation: 4 edges/wave, 8 cols/lane, fp16 out ------
__global__ void agg_v6(const unsigned* __restrict__ sorted, const int* __restrict__ start,
                       const __half* __restrict__ combo,    // [N][256]: hidden | hs_proj
                       const __half* __restrict__ hrcombo,  // [R][256]: rela | hr_proj
                       const __half* __restrict__ qrb,      // [B][128]: qr_proj
                       const float* __restrict__ Wa,
                       ushort_t* __restrict__ agg16, int N) {
    const int gtid = blockIdx.x * blockDim.x + threadIdx.x;
    const int wave = gtid >> 6;
    const int lane = threadIdx.x & 63;
    const int nwaves = (gridDim.x * blockDim.x) >> 6;
    const int grp = lane >> 4;        // 0..3 : edge slot within wave
    const int sl  = lane & 15;        // 0..15
    const int c   = sl * 8;           // 8 cols per lane
    __half2 wah[4];
    {
        const float4 w0 = *(const float4*)(Wa + c);
        const float4 w1 = *(const float4*)(Wa + c + 4);
        wah[0] = __floats2half2_rn(w0.x, w0.y);
        wah[1] = __floats2half2_rn(w0.z, w0.w);
        wah[2] = __floats2half2_rn(w1.x, w1.y);
        wah[3] = __floats2half2_rn(w1.z, w1.w);
    }
    const __half2 zero2 = __floats2half2_rn(0.f, 0.f);
    for (int n = wave; n < N; n += nwaves) {
        const int e0 = start[n], e1 = start[n + 1];
        float acc[8] = {0.f, 0.f, 0.f, 0.f, 0.f, 0.f, 0.f, 0.f};
        for (int e = e0 + grp; e < e1; e += 4) {
            const unsigned rec = sorted[e];
            const int sub  = rec & 0xFFFF;
            const int rel  = (rec >> 16) & 0x1FF;
            const int ridx = rec >> 25;
            const H8 uhid = *(const H8*)(combo + (size_t)sub * 256 + c);
            const H8 uhsp = *(const H8*)(combo + (size_t)sub * 256 + 128 + c);
            const H8 uhre = *(const H8*)(hrcombo + (size_t)rel * 256 + c);
            const H8 uhrp = *(const H8*)(hrcombo + (size_t)rel * 256 + 128 + c);
            const H8 uqrp = *(const H8*)(qrb + (size_t)ridx * 128 + c);
            __half2 d2 = zero2;
            #pragma unroll
            for (int j = 0; j < 4; ++j) {
                const __half2 p = hmax2(__hadd2(__hadd2(uhsp.h[j], uhrp.h[j]), uqrp.h[j]), zero2);
                d2 = __hfma2(p, wah[j], d2);
            }
            float part = __low2float(d2) + __high2float(d2);
            #pragma unroll
            for (int off = 8; off > 0; off >>= 1) part += __shfl_xor(part, off, 64);
            const float alpha = 1.f / (1.f + __expf(-part));
            #pragma unroll
            for (int j = 0; j < 4; ++j) {
                const __half2 m = __hadd2(uhid.h[j], uhre.h[j]);
                acc[j * 2]     = fmaf(__low2float(m),  alpha, acc[j * 2]);
                acc[j * 2 + 1] = fmaf(__high2float(m), alpha, acc[j * 2 + 1]);
            }
        }
        #pragma unroll
        for (int j = 0; j < 8; ++j) {   // combine the 4 edge slots
            acc[j] += __shfl_xor(acc[j], 16, 64);
            acc[j] += __shfl_xor(acc[j], 32, 64);
        }
        if (grp == 0) {
            uint4 pk;
            pk.x = pack_f16(acc[0], acc[1]); pk.y = pack_f16(acc[2], acc[3]);
            pk.z = pack_f16(acc[4], acc[5]); pk.w = pack_f16(acc[6], acc[7]);
            *(uint4*)(agg16 + (size_t)n * D + c) = pk;
        }
    }
}

extern "C" void kernel_launch(void* const* d_in, const int* in_sizes, int n_in,
                              void* d_out, int out_size, void* d_ws, size_t ws_size,
                              hipStream_t stream) {
    const int*   q_rel  = (const int*)d_in[0];
    const float* hidden = (const float*)d_in[1];
    const int*   edges  = (const int*)d_in[2];
    const float* rela   = (const float*)d_in[3];
    const float* Ws     = (const float*)d_in[4];
    const float* Wr     = (const float*)d_in[5];
    const float* Wqr_w  = (const float*)d_in[6];
    const float* Wqr_b  = (const float*)d_in[7];
    const float* Wa     = (const float*)d_in[8];
    const float* Wh     = (const float*)d_in[9];

    const int B = in_sizes[0];
    const int N = in_sizes[1] / D;
    const int E = in_sizes[2] / 6;
    const int R = in_sizes[3] / D;

    ushort_t* combo   = (ushort_t*)d_ws;                 // N*256 fp16
    ushort_t* hrcombo = combo + (size_t)N * 256;         // R*256 fp16
    ushort_t* qrb     = hrcombo + (size_t)R * 256;       // B*128 fp16
    ushort_t* Wt4     = qrb + (size_t)B * 128;           // 4*128*128 fp16
    ushort_t* agg16   = Wt4 + 4 * D * D;                 // N*128 fp16
    int* count  = (int*)(agg16 + (size_t)N * D);         // N
    int* bsum   = count + N;                             // 64
    int* start  = bsum + 64;                             // N+1
    int* cursor = start + N + 1;                         // N
    unsigned* rec    = (unsigned*)(cursor + N);          // E
    int*      obj    = (int*)(rec + E);                  // E
    unsigned* sorted = (unsigned*)(obj + E);             // E

    // CSR build
    (void)hipMemsetAsync(count, 0, (size_t)N * sizeof(int), stream);
    pack_hist<<<1024, 256, 0, stream>>>(edges, rec, obj, count, E);
    const int G = (N + 1023) / 1024;
    scan_partial<<<G, 1024, 0, stream>>>(count, bsum, N);
    scan_final<<<G, 1024, 0, stream>>>(count, bsum, start, cursor, N, G);
    scatter2<<<1024, 256, 0, stream>>>(rec, obj, cursor, sorted, E);

    // weight prep + MFMA projections (fused fp16 combo production)
    prep_wt<<<4, 256, 0, stream>>>(Ws, Wr, Wqr_w, Wh, Wt4);
    const int TB = (N + 63) / 64;
    gemm_t<1><<<TB, 256, 0, stream>>>(hidden, nullptr, Wt4, nullptr, nullptr, combo, N, 0);
    gemm_t<1><<<(R + 63) / 64, 256, 0, stream>>>(rela, nullptr, Wt4 + D * D, nullptr, nullptr, hrcombo, R, 0);
    gemm_t<2><<<(B + 63) / 64, 256, 0, stream>>>(rela, nullptr, Wt4 + 2 * D * D, Wqr_b, q_rel, qrb, B, 0);

    // gather aggregation -> fp16 agg rows
    agg_v6<<<2048, 256, 0, stream>>>(sorted, start, (const __half*)combo,
                                     (const __half*)hrcombo, (const __half*)qrb, Wa,
                                     agg16, N);

    // out = relu(agg @ Wh), fp16 in / f32 out, MFMA
    gemm_t<3><<<TB, 256, 0, stream>>>(nullptr, agg16, Wt4 + 3 * D * D, nullptr, nullptr,
                                      d_out, N, 1);
}

// Round 9
// 144.005 us; speedup vs baseline: 1.5021x; 1.1158x over previous
//
#include <hip/hip_runtime.h>
#include <hip/hip_fp16.h>
#include <math.h>
#include <stdint.h>

#define D 128
typedef __attribute__((ext_vector_type(8))) _Float16 f16x8;
typedef __attribute__((ext_vector_type(4))) float f32x4;
typedef unsigned short ushort_t;

__device__ inline unsigned pack_f16(float a, float b) {
    __half2 h = __floats2half2_rn(a, b);
    return __builtin_bit_cast(unsigned, h);
}
__device__ inline ushort_t f16_of(float f) {
    __half h = __float2half_rn(f);
    return __builtin_bit_cast(ushort_t, h);
}
__device__ inline __half2 hmax2(__half2 a, __half2 b) {
    unsigned ua = __builtin_bit_cast(unsigned, a);
    unsigned ub = __builtin_bit_cast(unsigned, b);
    unsigned r;
    asm("v_pk_max_f16 %0, %1, %2" : "=v"(r) : "v"(ua), "v"(ub));
    return __builtin_bit_cast(__half2, r);
}

struct __align__(16) H8 { __half2 h[4]; };

// ---------------- edge pack + histogram (reads 24B/edge once) ----------------
// rec = sub:16 | rel:9 | r_idx:7
__global__ void pack_hist(const int* __restrict__ edges, unsigned* __restrict__ rec,
                          int* __restrict__ obj, int* __restrict__ count, int E) {
    const int i = blockIdx.x * blockDim.x + threadIdx.x;
    const int stride = gridDim.x * blockDim.x;
    const uint2* e2 = (const uint2*)edges;
    for (int e = i; e < E; e += stride) {
        const unsigned r_idx = e2[e * 3 + 0].x;
        const unsigned rel   = e2[e * 3 + 1].x;
        const uint2 so       = e2[e * 3 + 2];     // .x=sub .y=obj
        rec[e] = so.x | (rel << 16) | (r_idx << 25);
        obj[e] = (int)so.y;
        atomicAdd(&count[so.y], 1);
    }
}

// ---------------- 2-phase exclusive scan ----------------
__global__ void scan_partial(const int* __restrict__ count, int* __restrict__ bsum, int M) {
    __shared__ int wsum[16];
    const int t = threadIdx.x, lane = t & 63, w = t >> 6;
    const int i = blockIdx.x * 1024 + t;
    int v = (i < M) ? count[i] : 0;
    #pragma unroll
    for (int off = 32; off > 0; off >>= 1) v += __shfl_xor(v, off, 64);
    if (lane == 0) wsum[w] = v;
    __syncthreads();
    if (w == 0) {
        int s = (lane < 16) ? wsum[lane] : 0;
        #pragma unroll
        for (int off = 8; off > 0; off >>= 1) s += __shfl_xor(s, off, 16);
        if (lane == 0) bsum[blockIdx.x] = s;
    }
}

__global__ void scan_final(const int* __restrict__ count, const int* __restrict__ bsum,
                           int* __restrict__ start, int* __restrict__ cursor, int M, int G) {
    __shared__ int wsum[16];
    __shared__ int sboff;
    const int t = threadIdx.x, lane = t & 63, w = t >> 6;
    const int i = blockIdx.x * 1024 + t;
    const int v = (i < M) ? count[i] : 0;
    if (w == 0) {
        int bv = (lane < G) ? bsum[lane] : 0;
        int bx = bv;
        #pragma unroll
        for (int off = 1; off < 64; off <<= 1) {
            int y = __shfl_up(bx, off, 64);
            if (lane >= off) bx += y;
        }
        if (lane == (blockIdx.x & 63)) sboff = bx - bv;
    }
    int x = v;
    #pragma unroll
    for (int off = 1; off < 64; off <<= 1) {
        int y = __shfl_up(x, off, 64);
        if (lane >= off) x += y;
    }
    if (lane == 63) wsum[w] = x;
    __syncthreads();
    if (w == 0) {
        int s = (lane < 16) ? wsum[lane] : 0;
        int xs = s;
        #pragma unroll
        for (int off = 1; off < 16; off <<= 1) {
            int y = __shfl_up(xs, off, 64);
            if (lane >= off) xs += y;
        }
        if (lane < 16) wsum[lane] = xs - s;
    }
    __syncthreads();
    const int excl = x - v + wsum[w] + sboff;
    if (i < M) {
        start[i] = excl;
        cursor[i] = excl;
        if (i == M - 1) start[M] = excl + v;
    }
}

// ---------------- scatter packed recs into CSR order ----------------
__global__ void scatter2(const unsigned* __restrict__ rec, const int* __restrict__ obj,
                         int* __restrict__ cursor, unsigned* __restrict__ sorted, int E) {
    const int i = blockIdx.x * blockDim.x + threadIdx.x;
    const int stride = gridDim.x * blockDim.x;
    for (int e = i; e < E; e += stride) {
        const int pos = atomicAdd(&cursor[obj[e]], 1);
        sorted[pos] = rec[e];
    }
}

// ---------------- W -> W^T fp16 prep: blocks 0..3 -> Ws, Wr, Wqr, Wh ----------------
__global__ void prep_wt(const float* __restrict__ W0, const float* __restrict__ W1,
                        const float* __restrict__ W2, const float* __restrict__ W3,
                        ushort_t* __restrict__ Wt4) {
    __shared__ ushort_t sT[D * D];
    const float* src = blockIdx.x == 0 ? W0 : blockIdx.x == 1 ? W1 : blockIdx.x == 2 ? W2 : W3;
    ushort_t* dst = Wt4 + (size_t)blockIdx.x * (D * D);
    const int t = threadIdx.x;
    for (int i = t; i < D * D; i += 256) {
        const int k = i >> 7, col = i & 127;
        sT[col * D + k] = f16_of(src[i]);
    }
    __syncthreads();
    const uint4* s8 = (const uint4*)sT;
    uint4* d8 = (uint4*)dst;
    for (int i = t; i < D * D / 8; i += 256) d8[i] = s8[i];
}

// ---- LDS staging helpers (XOR-swizzled layout, 256B rows) ----
__device__ inline void stage_w(ushort_t* sW, const ushort_t* Wt, int t) {
    const uint4* src = (const uint4*)Wt;
    for (int s = t; s < 2048; s += 256) {
        const int col = s >> 4;
        const int off = (s & 15) * 16;
        *(uint4*)((char*)sW + col * 256 + (off ^ ((col & 7) << 4))) = src[s];
    }
}
__device__ inline void stage_x(ushort_t* sX, const float* X, const int* rowidx,
                               int r0, int M, int t) {
    const int row = t >> 2, q = t & 3;
    const int gr = r0 + row;
    if (gr < M) {
        const int src = rowidx ? rowidx[gr] : gr;
        const float* xp = X + (size_t)src * D + q * 32;
        #pragma unroll
        for (int s = 0; s < 4; ++s) {
            const float4 v0 = *(const float4*)(xp + s * 8);
            const float4 v1 = *(const float4*)(xp + s * 8 + 4);
            uint4 pk;
            pk.x = pack_f16(v0.x, v0.y); pk.y = pack_f16(v0.z, v0.w);
            pk.z = pack_f16(v1.x, v1.y); pk.w = pack_f16(v1.z, v1.w);
            const int off = q * 64 + s * 16;
            *(uint4*)((char*)sX + row * 256 + (off ^ ((row & 7) << 4))) = pk;
        }
    }
}

// ---------------- dual-W MFMA projection: Y = [X@WA | X@WB] fp16 combo ----------------
__global__ __launch_bounds__(256, 2)
void gemm_dual(const float* __restrict__ X, const ushort_t* __restrict__ WtA,
               const ushort_t* __restrict__ WtB, ushort_t* __restrict__ Y, int M) {
    __shared__ ushort_t sWA[D * D];  // 32 KB
    __shared__ ushort_t sWB[D * D];  // 32 KB
    __shared__ ushort_t sX[64 * D];  // 16 KB
    const int t = threadIdx.x;
    stage_w(sWA, WtA, t);
    stage_w(sWB, WtB, t);
    const int wave = t >> 6, lane = t & 63;
    const int l15 = lane & 15, lg = lane >> 4;
    __syncthreads();
    for (int r0 = blockIdx.x * 64; r0 < M; r0 += gridDim.x * 64) {
        stage_x(sX, X, nullptr, r0, M, t);
        __syncthreads();
        f32x4 accA[8], accB[8];
        #pragma unroll
        for (int ct = 0; ct < 8; ++ct) {
            accA[ct] = (f32x4){0.f, 0.f, 0.f, 0.f};
            accB[ct] = (f32x4){0.f, 0.f, 0.f, 0.f};
        }
        #pragma unroll
        for (int kc = 0; kc < 4; ++kc) {
            const int koff = kc * 64 + lg * 16;
            const int arow = wave * 16 + l15;
            const f16x8 afrag = *(const f16x8*)((char*)sX + arow * 256 + (koff ^ ((arow & 7) << 4)));
            #pragma unroll
            for (int ct = 0; ct < 8; ++ct) {
                const int col = ct * 16 + l15;
                const int sw = koff ^ ((col & 7) << 4);
                const f16x8 bfA = *(const f16x8*)((char*)sWA + col * 256 + sw);
                const f16x8 bfB = *(const f16x8*)((char*)sWB + col * 256 + sw);
                accA[ct] = __builtin_amdgcn_mfma_f32_16x16x32_f16(afrag, bfA, accA[ct], 0, 0, 0);
                accB[ct] = __builtin_amdgcn_mfma_f32_16x16x32_f16(afrag, bfB, accB[ct], 0, 0, 0);
            }
        }
        __syncthreads();
        #pragma unroll
        for (int q2 = 0; q2 < 4; ++q2) {
            const int gr2 = r0 + wave * 16 + lg * 4 + q2;
            if (gr2 < M) {
                #pragma unroll
                for (int ct = 0; ct < 8; ++ct) {
                    const int col = ct * 16 + l15;
                    Y[(size_t)gr2 * 256 + col]       = f16_of(accA[ct][q2]);
                    Y[(size_t)gr2 * 256 + 128 + col] = f16_of(accB[ct][q2]);
                }
            }
        }
    }
}

// ---------------- merged R/B projection: blocks 0..G-1 dual (rela), last block qrb ------
__global__ __launch_bounds__(256, 2)
void gemm_rb(const float* __restrict__ Xr, const ushort_t* __restrict__ WtA,
             const ushort_t* __restrict__ WtB, ushort_t* __restrict__ Yr, int Mr,
             const ushort_t* __restrict__ WtQ, const float* __restrict__ bias,
             const int* __restrict__ q_rel, ushort_t* __restrict__ Yq, int Mq) {
    __shared__ ushort_t sWA[D * D];
    __shared__ ushort_t sWB[D * D];
    __shared__ ushort_t sX[64 * D];
    const int t = threadIdx.x;
    const int wave = t >> 6, lane = t & 63;
    const int l15 = lane & 15, lg = lane >> 4;
    const int r0 = blockIdx.x * 64;
    if (r0 < Mr) {   // dual path: Yr = [Xr@WA | Xr@WB]
        stage_w(sWA, WtA, t);
        stage_w(sWB, WtB, t);
        __syncthreads();
        stage_x(sX, Xr, nullptr, r0, Mr, t);
        __syncthreads();
        f32x4 accA[8], accB[8];
        #pragma unroll
        for (int ct = 0; ct < 8; ++ct) {
            accA[ct] = (f32x4){0.f, 0.f, 0.f, 0.f};
            accB[ct] = (f32x4){0.f, 0.f, 0.f, 0.f};
        }
        #pragma unroll
        for (int kc = 0; kc < 4; ++kc) {
            const int koff = kc * 64 + lg * 16;
            const int arow = wave * 16 + l15;
            const f16x8 afrag = *(const f16x8*)((char*)sX + arow * 256 + (koff ^ ((arow & 7) << 4)));
            #pragma unroll
            for (int ct = 0; ct < 8; ++ct) {
                const int col = ct * 16 + l15;
                const int sw = koff ^ ((col & 7) << 4);
                const f16x8 bfA = *(const f16x8*)((char*)sWA + col * 256 + sw);
                const f16x8 bfB = *(const f16x8*)((char*)sWB + col * 256 + sw);
                accA[ct] = __builtin_amdgcn_mfma_f32_16x16x32_f16(afrag, bfA, accA[ct], 0, 0, 0);
                accB[ct] = __builtin_amdgcn_mfma_f32_16x16x32_f16(afrag, bfB, accB[ct], 0, 0, 0);
            }
        }
        #pragma unroll
        for (int q2 = 0; q2 < 4; ++q2) {
            const int gr2 = r0 + wave * 16 + lg * 4 + q2;
            if (gr2 < Mr) {
                #pragma unroll
                for (int ct = 0; ct < 8; ++ct) {
                    const int col = ct * 16 + l15;
                    Yr[(size_t)gr2 * 256 + col]       = f16_of(accA[ct][q2]);
                    Yr[(size_t)gr2 * 256 + 128 + col] = f16_of(accB[ct][q2]);
                }
            }
        }
    } else {   // q path: Yq = Xr[q_rel] @ WQ + bias
        stage_w(sWA, WtQ, t);
        __syncthreads();
        stage_x(sX, Xr, q_rel, 0, Mq, t);
        __syncthreads();
        f32x4 acc[8];
        #pragma unroll
        for (int ct = 0; ct < 8; ++ct) acc[ct] = (f32x4){0.f, 0.f, 0.f, 0.f};
        #pragma unroll
        for (int kc = 0; kc < 4; ++kc) {
            const int koff = kc * 64 + lg * 16;
            const int arow = wave * 16 + l15;
            const f16x8 afrag = *(const f16x8*)((char*)sX + arow * 256 + (koff ^ ((arow & 7) << 4)));
            #pragma unroll
            for (int ct = 0; ct < 8; ++ct) {
                const int col = ct * 16 + l15;
                const f16x8 bf = *(const f16x8*)((char*)sWA + col * 256 + ((koff) ^ ((col & 7) << 4)));
                acc[ct] = __builtin_amdgcn_mfma_f32_16x16x32_f16(afrag, bf, acc[ct], 0, 0, 0);
            }
        }
        #pragma unroll
        for (int q2 = 0; q2 < 4; ++q2) {
            const int gr2 = wave * 16 + lg * 4 + q2;
            if (gr2 < Mq) {
                #pragma unroll
                for (int ct = 0; ct < 8; ++ct) {
                    const int col = ct * 16 + l15;
                    Yq[(size_t)gr2 * 128 + col] = f16_of(acc[ct][q2] + bias[col]);
                }
            }
        }
    }
}

// ------- per-node aggregation, final: out = relu(sum alpha*(hw[sub]+rw[rel])) f32 -------
__global__ void agg_v7(const unsigned* __restrict__ sorted, const int* __restrict__ start,
                       const __half* __restrict__ combo,    // [N][256]: hw | hs_proj
                       const __half* __restrict__ hrcombo,  // [R][256]: rw | hr_proj
                       const __half* __restrict__ qrb,      // [B][128]: qr_proj
                       const float* __restrict__ Wa,
                       float* __restrict__ out, int N) {
    const int gtid = blockIdx.x * blockDim.x + threadIdx.x;
    const int wave = gtid >> 6;
    const int lane = threadIdx.x & 63;
    const int nwaves = (gridDim.x * blockDim.x) >> 6;
    const int grp = lane >> 4;        // 0..3 : edge slot within wave
    const int sl  = lane & 15;        // 0..15
    const int c   = sl * 8;           // 8 cols per lane
    __half2 wah[4];
    {
        const float4 w0 = *(const float4*)(Wa + c);
        const float4 w1 = *(const float4*)(Wa + c + 4);
        wah[0] = __floats2half2_rn(w0.x, w0.y);
        wah[1] = __floats2half2_rn(w0.z, w0.w);
        wah[2] = __floats2half2_rn(w1.x, w1.y);
        wah[3] = __floats2half2_rn(w1.z, w1.w);
    }
    const __half2 zero2 = __floats2half2_rn(0.f, 0.f);
    for (int n = wave; n < N; n += nwaves) {
        const int e0 = start[n], e1 = start[n + 1];
        float acc[8] = {0.f, 0.f, 0.f, 0.f, 0.f, 0.f, 0.f, 0.f};
        for (int e = e0 + grp; e < e1; e += 4) {
            const unsigned rec = sorted[e];
            const int sub  = rec & 0xFFFF;
            const int rel  = (rec >> 16) & 0x1FF;
            const int ridx = rec >> 25;
            const H8 uhw  = *(const H8*)(combo + (size_t)sub * 256 + c);
            const H8 uhsp = *(const H8*)(combo + (size_t)sub * 256 + 128 + c);
            const H8 urw  = *(const H8*)(hrcombo + (size_t)rel * 256 + c);
            const H8 uhrp = *(const H8*)(hrcombo + (size_t)rel * 256 + 128 + c);
            const H8 uqrp = *(const H8*)(qrb + (size_t)ridx * 128 + c);
            __half2 d2 = zero2;
            #pragma unroll
            for (int j = 0; j < 4; ++j) {
                const __half2 p = hmax2(__hadd2(__hadd2(uhsp.h[j], uhrp.h[j]), uqrp.h[j]), zero2);
                d2 = __hfma2(p, wah[j], d2);
            }
            float part = __low2float(d2) + __high2float(d2);
            #pragma unroll
            for (int off = 8; off > 0; off >>= 1) part += __shfl_xor(part, off, 64);
            const float alpha = 1.f / (1.f + __expf(-part));
            #pragma unroll
            for (int j = 0; j < 4; ++j) {
                const __half2 m = __hadd2(uhw.h[j], urw.h[j]);
                acc[j * 2]     = fmaf(__low2float(m),  alpha, acc[j * 2]);
                acc[j * 2 + 1] = fmaf(__high2float(m), alpha, acc[j * 2 + 1]);
            }
        }
        #pragma unroll
        for (int j = 0; j < 8; ++j) {   // combine the 4 edge slots
            acc[j] += __shfl_xor(acc[j], 16, 64);
            acc[j] += __shfl_xor(acc[j], 32, 64);
        }
        if (grp == 0) {
            const float4 o0 = make_float4(fmaxf(acc[0], 0.f), fmaxf(acc[1], 0.f),
                                          fmaxf(acc[2], 0.f), fmaxf(acc[3], 0.f));
            const float4 o1 = make_float4(fmaxf(acc[4], 0.f), fmaxf(acc[5], 0.f),
                                          fmaxf(acc[6], 0.f), fmaxf(acc[7], 0.f));
            *(float4*)(out + (size_t)n * D + c)     = o0;
            *(float4*)(out + (size_t)n * D + c + 4) = o1;
        }
    }
}

extern "C" void kernel_launch(void* const* d_in, const int* in_sizes, int n_in,
                              void* d_out, int out_size, void* d_ws, size_t ws_size,
                              hipStream_t stream) {
    const int*   q_rel  = (const int*)d_in[0];
    const float* hidden = (const float*)d_in[1];
    const int*   edges  = (const int*)d_in[2];
    const float* rela   = (const float*)d_in[3];
    const float* Ws     = (const float*)d_in[4];
    const float* Wr     = (const float*)d_in[5];
    const float* Wqr_w  = (const float*)d_in[6];
    const float* Wqr_b  = (const float*)d_in[7];
    const float* Wa     = (const float*)d_in[8];
    const float* Wh     = (const float*)d_in[9];

    const int B = in_sizes[0];
    const int N = in_sizes[1] / D;
    const int E = in_sizes[2] / 6;
    const int R = in_sizes[3] / D;

    ushort_t* combo   = (ushort_t*)d_ws;                 // N*256 fp16: hw | hs_proj
    ushort_t* hrcombo = combo + (size_t)N * 256;         // R*256 fp16: rw | hr_proj
    ushort_t* qrb     = hrcombo + (size_t)R * 256;       // B*128 fp16
    ushort_t* Wt4     = qrb + (size_t)B * 128;           // 4*128*128 fp16: Ws,Wr,Wqr,Wh ^T
    int* count  = (int*)(Wt4 + 4 * D * D);               // N
    int* bsum   = count + N;                             // 64
    int* start  = bsum + 64;                             // N+1
    int* cursor = start + N + 1;                         // N
    unsigned* rec    = (unsigned*)(cursor + N);          // E
    int*      obj    = (int*)(rec + E);                  // E
    unsigned* sorted = (unsigned*)(obj + E);             // E

    const ushort_t* WsT  = Wt4;
    const ushort_t* WrT  = Wt4 + D * D;
    const ushort_t* WqrT = Wt4 + 2 * D * D;
    const ushort_t* WhT  = Wt4 + 3 * D * D;

    // CSR build
    (void)hipMemsetAsync(count, 0, (size_t)N * sizeof(int), stream);
    pack_hist<<<1024, 256, 0, stream>>>(edges, rec, obj, count, E);
    const int G = (N + 1023) / 1024;
    scan_partial<<<G, 1024, 0, stream>>>(count, bsum, N);
    scan_final<<<G, 1024, 0, stream>>>(count, bsum, start, cursor, N, G);
    scatter2<<<1024, 256, 0, stream>>>(rec, obj, cursor, sorted, E);

    // weight prep + fused projections
    prep_wt<<<4, 256, 0, stream>>>(Ws, Wr, Wqr_w, Wh, Wt4);
    const int TB = (N + 63) / 64;
    gemm_dual<<<TB, 256, 0, stream>>>(hidden, WhT, WsT, combo, N);       // [hw | hs_proj]
    const int RBLK = (R + 63) / 64;
    gemm_rb<<<RBLK + 1, 256, 0, stream>>>(rela, WhT, WrT, hrcombo, R,    // [rw | hr_proj]
                                          WqrT, Wqr_b, q_rel, qrb, B);   // qr_proj

    // final: gather-aggregate + relu -> d_out (no separate GEMM pass)
    agg_v7<<<2048, 256, 0, stream>>>(sorted, start, (const __half*)combo,
                                     (const __half*)hrcombo, (const __half*)qrb, Wa,
                                     (float*)d_out, N);
}

// Round 10
// 142.222 us; speedup vs baseline: 1.5209x; 1.0125x over previous
//
#include <hip/hip_runtime.h>
#include <hip/hip_fp16.h>
#include <math.h>
#include <stdint.h>

#define D 128
typedef __attribute__((ext_vector_type(8))) _Float16 f16x8;
typedef __attribute__((ext_vector_type(4))) float f32x4;
typedef unsigned short ushort_t;

__device__ inline unsigned pack_f16(float a, float b) {
    __half2 h = __floats2half2_rn(a, b);
    return __builtin_bit_cast(unsigned, h);
}
__device__ inline ushort_t f16_of(float f) {
    __half h = __float2half_rn(f);
    return __builtin_bit_cast(ushort_t, h);
}
__device__ inline __half2 hmax2(__half2 a, __half2 b) {
    unsigned ua = __builtin_bit_cast(unsigned, a);
    unsigned ub = __builtin_bit_cast(unsigned, b);
    unsigned r;
    asm("v_pk_max_f16 %0, %1, %2" : "=v"(r) : "v"(ua), "v"(ub));
    return __builtin_bit_cast(__half2, r);
}

struct __align__(16) H8 { __half2 h[4]; };

// ------------- fused: W->W^T fp16 prep (blocks 0..3) + edge pack/hist (blocks 4+) -------
// rec = sub:16 | rel:9 | r_idx:7
__global__ void pack_prep(const int* __restrict__ edges, unsigned* __restrict__ rec,
                          int* __restrict__ obj, int* __restrict__ count, int E,
                          const float* __restrict__ W0, const float* __restrict__ W1,
                          const float* __restrict__ W2, const float* __restrict__ W3,
                          ushort_t* __restrict__ Wt4) {
    __shared__ ushort_t sT[D * D];
    const int t = threadIdx.x;
    if (blockIdx.x < 4) {   // transpose+convert one weight matrix
        const float* src = blockIdx.x == 0 ? W0 : blockIdx.x == 1 ? W1 : blockIdx.x == 2 ? W2 : W3;
        ushort_t* dst = Wt4 + (size_t)blockIdx.x * (D * D);
        for (int i = t; i < D * D; i += 256) {
            const int k = i >> 7, col = i & 127;
            sT[col * D + k] = f16_of(src[i]);
        }
        __syncthreads();
        const uint4* s8 = (const uint4*)sT;
        uint4* d8 = (uint4*)dst;
        for (int i = t; i < D * D / 8; i += 256) d8[i] = s8[i];
    } else {                // pack edges + histogram
        const int i0 = (blockIdx.x - 4) * blockDim.x + t;
        const int stride = (gridDim.x - 4) * blockDim.x;
        const uint2* e2 = (const uint2*)edges;
        for (int e = i0; e < E; e += stride) {
            const unsigned r_idx = e2[e * 3 + 0].x;
            const unsigned rel   = e2[e * 3 + 1].x;
            const uint2 so       = e2[e * 3 + 2];     // .x=sub .y=obj
            rec[e] = so.x | (rel << 16) | (r_idx << 25);
            obj[e] = (int)so.y;
            atomicAdd(&count[so.y], 1);
        }
    }
}

// ---------------- 2-phase exclusive scan ----------------
__global__ void scan_partial(const int* __restrict__ count, int* __restrict__ bsum, int M) {
    __shared__ int wsum[16];
    const int t = threadIdx.x, lane = t & 63, w = t >> 6;
    const int i = blockIdx.x * 1024 + t;
    int v = (i < M) ? count[i] : 0;
    #pragma unroll
    for (int off = 32; off > 0; off >>= 1) v += __shfl_xor(v, off, 64);
    if (lane == 0) wsum[w] = v;
    __syncthreads();
    if (w == 0) {
        int s = (lane < 16) ? wsum[lane] : 0;
        #pragma unroll
        for (int off = 8; off > 0; off >>= 1) s += __shfl_xor(s, off, 16);
        if (lane == 0) bsum[blockIdx.x] = s;
    }
}

__global__ void scan_final(const int* __restrict__ count, const int* __restrict__ bsum,
                           int* __restrict__ start, int* __restrict__ cursor, int M, int G) {
    __shared__ int wsum[16];
    __shared__ int sboff;
    const int t = threadIdx.x, lane = t & 63, w = t >> 6;
    const int i = blockIdx.x * 1024 + t;
    const int v = (i < M) ? count[i] : 0;
    if (w == 0) {
        int bv = (lane < G) ? bsum[lane] : 0;
        int bx = bv;
        #pragma unroll
        for (int off = 1; off < 64; off <<= 1) {
            int y = __shfl_up(bx, off, 64);
            if (lane >= off) bx += y;
        }
        if (lane == (blockIdx.x & 63)) sboff = bx - bv;
    }
    int x = v;
    #pragma unroll
    for (int off = 1; off < 64; off <<= 1) {
        int y = __shfl_up(x, off, 64);
        if (lane >= off) x += y;
    }
    if (lane == 63) wsum[w] = x;
    __syncthreads();
    if (w == 0) {
        int s = (lane < 16) ? wsum[lane] : 0;
        int xs = s;
        #pragma unroll
        for (int off = 1; off < 16; off <<= 1) {
            int y = __shfl_up(xs, off, 64);
            if (lane >= off) xs += y;
        }
        if (lane < 16) wsum[lane] = xs - s;
    }
    __syncthreads();
    const int excl = x - v + wsum[w] + sboff;
    if (i < M) {
        start[i] = excl;
        cursor[i] = excl;
        if (i == M - 1) start[M] = excl + v;
    }
}

// ---------------- scatter packed recs into CSR order ----------------
__global__ void scatter2(const unsigned* __restrict__ rec, const int* __restrict__ obj,
                         int* __restrict__ cursor, unsigned* __restrict__ sorted, int E) {
    const int i = blockIdx.x * blockDim.x + threadIdx.x;
    const int stride = gridDim.x * blockDim.x;
    for (int e = i; e < E; e += stride) {
        const int pos = atomicAdd(&cursor[obj[e]], 1);
        sorted[pos] = rec[e];
    }
}

// ---- LDS staging helpers (XOR-swizzled layout, 256B rows) ----
__device__ inline void stage_w(ushort_t* sW, const ushort_t* Wt, int t) {
    const uint4* src = (const uint4*)Wt;
    for (int s = t; s < 2048; s += 256) {
        const int col = s >> 4;
        const int off = (s & 15) * 16;
        *(uint4*)((char*)sW + col * 256 + (off ^ ((col & 7) << 4))) = src[s];
    }
}
__device__ inline void stage_x(ushort_t* sX, const float* X, const int* rowidx,
                               int r0, int M, int t) {
    const int row = t >> 2, q = t & 3;
    const int gr = r0 + row;
    if (gr < M) {
        const int src = rowidx ? rowidx[gr] : gr;
        const float* xp = X + (size_t)src * D + q * 32;
        #pragma unroll
        for (int s = 0; s < 4; ++s) {
            const float4 v0 = *(const float4*)(xp + s * 8);
            const float4 v1 = *(const float4*)(xp + s * 8 + 4);
            uint4 pk;
            pk.x = pack_f16(v0.x, v0.y); pk.y = pack_f16(v0.z, v0.w);
            pk.z = pack_f16(v1.x, v1.y); pk.w = pack_f16(v1.z, v1.w);
            const int off = q * 64 + s * 16;
            *(uint4*)((char*)sX + row * 256 + (off ^ ((row & 7) << 4))) = pk;
        }
    }
}

// ---------------- all projections in one launch ----------------
// blocks [0,TB):       combo   = [hidden@Wh | hidden@Ws]
// blocks [TB,TB+RB):   hrcombo = [rela@Wh   | rela@Wr]
// block  TB+RB:        qrb     = rela[q_rel]@Wqr + bias
__global__ __launch_bounds__(256, 2)
void gemm_all(const float* __restrict__ hidden, const float* __restrict__ rela,
              const ushort_t* __restrict__ Wt4, const float* __restrict__ bias,
              const int* __restrict__ q_rel,
              ushort_t* __restrict__ combo, ushort_t* __restrict__ hrcombo,
              ushort_t* __restrict__ qrb, int N, int R, int B, int TB, int RB) {
    __shared__ ushort_t sWA[D * D];  // 32 KB
    __shared__ ushort_t sWB[D * D];  // 32 KB
    __shared__ ushort_t sX[64 * D];  // 16 KB
    const int t = threadIdx.x;
    const int wave = t >> 6, lane = t & 63;
    const int l15 = lane & 15, lg = lane >> 4;
    const int bid = blockIdx.x;

    const bool qpath = (bid == TB + RB);
    const float* X   = (bid < TB) ? hidden : rela;
    const int    M   = (bid < TB) ? N : (qpath ? B : R);
    const int    r0  = (bid < TB) ? bid * 64 : (qpath ? 0 : (bid - TB) * 64);
    ushort_t*    Y   = (bid < TB) ? combo : (qpath ? qrb : hrcombo);

    if (!qpath) {
        stage_w(sWA, Wt4 + 3 * D * D, t);                         // Wh^T
        stage_w(sWB, (bid < TB) ? Wt4 : (Wt4 + D * D), t);        // Ws^T or Wr^T
        stage_x(sX, X, nullptr, r0, M, t);
        __syncthreads();
        f32x4 accA[8], accB[8];
        #pragma unroll
        for (int ct = 0; ct < 8; ++ct) {
            accA[ct] = (f32x4){0.f, 0.f, 0.f, 0.f};
            accB[ct] = (f32x4){0.f, 0.f, 0.f, 0.f};
        }
        #pragma unroll
        for (int kc = 0; kc < 4; ++kc) {
            const int koff = kc * 64 + lg * 16;
            const int arow = wave * 16 + l15;
            const f16x8 afrag = *(const f16x8*)((char*)sX + arow * 256 + (koff ^ ((arow & 7) << 4)));
            #pragma unroll
            for (int ct = 0; ct < 8; ++ct) {
                const int col = ct * 16 + l15;
                const int sw = koff ^ ((col & 7) << 4);
                const f16x8 bfA = *(const f16x8*)((char*)sWA + col * 256 + sw);
                const f16x8 bfB = *(const f16x8*)((char*)sWB + col * 256 + sw);
                accA[ct] = __builtin_amdgcn_mfma_f32_16x16x32_f16(afrag, bfA, accA[ct], 0, 0, 0);
                accB[ct] = __builtin_amdgcn_mfma_f32_16x16x32_f16(afrag, bfB, accB[ct], 0, 0, 0);
            }
        }
        #pragma unroll
        for (int q2 = 0; q2 < 4; ++q2) {
            const int gr2 = r0 + wave * 16 + lg * 4 + q2;
            if (gr2 < M) {
                #pragma unroll
                for (int ct = 0; ct < 8; ++ct) {
                    const int col = ct * 16 + l15;
                    Y[(size_t)gr2 * 256 + col]       = f16_of(accA[ct][q2]);   // @Wh
                    Y[(size_t)gr2 * 256 + 128 + col] = f16_of(accB[ct][q2]);   // @Ws / @Wr
                }
            }
        }
    } else {
        stage_w(sWA, Wt4 + 2 * D * D, t);                         // Wqr^T
        stage_x(sX, X, q_rel, 0, M, t);
        __syncthreads();
        f32x4 acc[8];
        #pragma unroll
        for (int ct = 0; ct < 8; ++ct) acc[ct] = (f32x4){0.f, 0.f, 0.f, 0.f};
        #pragma unroll
        for (int kc = 0; kc < 4; ++kc) {
            const int koff = kc * 64 + lg * 16;
            const int arow = wave * 16 + l15;
            const f16x8 afrag = *(const f16x8*)((char*)sX + arow * 256 + (koff ^ ((arow & 7) << 4)));
            #pragma unroll
            for (int ct = 0; ct < 8; ++ct) {
                const int col = ct * 16 + l15;
                const f16x8 bf = *(const f16x8*)((char*)sWA + col * 256 + (koff ^ ((col & 7) << 4)));
                acc[ct] = __builtin_amdgcn_mfma_f32_16x16x32_f16(afrag, bf, acc[ct], 0, 0, 0);
            }
        }
        #pragma unroll
        for (int q2 = 0; q2 < 4; ++q2) {
            const int gr2 = wave * 16 + lg * 4 + q2;
            if (gr2 < M) {
                #pragma unroll
                for (int ct = 0; ct < 8; ++ct) {
                    const int col = ct * 16 + l15;
                    Y[(size_t)gr2 * 128 + col] = f16_of(acc[ct][q2] + bias[col]);
                }
            }
        }
    }
}

// ------- per-node aggregation, 2-deep pipelined: out = relu(sum a*(hw+rw)) f32 -------
__global__ void agg_v8(const unsigned* __restrict__ sorted, const int* __restrict__ start,
                       const __half* __restrict__ combo,    // [N][256]: hw | hs_proj
                       const __half* __restrict__ hrcombo,  // [R][256]: rw | hr_proj
                       const __half* __restrict__ qrb,      // [B][128]: qr_proj
                       const float* __restrict__ Wa,
                       float* __restrict__ out, int N) {
    const int gtid = blockIdx.x * blockDim.x + threadIdx.x;
    const int wave = gtid >> 6;
    const int lane = threadIdx.x & 63;
    const int nwaves = (gridDim.x * blockDim.x) >> 6;
    const int grp = lane >> 4;        // 0..3 : edge slot within wave
    const int sl  = lane & 15;        // 0..15
    const int c   = sl * 8;           // 8 cols per lane
    __half2 wah[4];
    {
        const float4 w0 = *(const float4*)(Wa + c);
        const float4 w1 = *(const float4*)(Wa + c + 4);
        wah[0] = __floats2half2_rn(w0.x, w0.y);
        wah[1] = __floats2half2_rn(w0.z, w0.w);
        wah[2] = __floats2half2_rn(w1.x, w1.y);
        wah[3] = __floats2half2_rn(w1.z, w1.w);
    }
    const __half2 zero2 = __floats2half2_rn(0.f, 0.f);
    for (int n = wave; n < N; n += nwaves) {
        const int e0 = start[n], e1 = start[n + 1];
        float acc[8] = {0.f, 0.f, 0.f, 0.f, 0.f, 0.f, 0.f, 0.f};
        int e = e0 + grp;
        if (e < e1) {
            unsigned rec = sorted[e];
            int sub = rec & 0xFFFF, rel = (rec >> 16) & 0x1FF, ridx = rec >> 25;
            H8 uhw  = *(const H8*)(combo + (size_t)sub * 256 + c);
            H8 uhsp = *(const H8*)(combo + (size_t)sub * 256 + 128 + c);
            H8 urw  = *(const H8*)(hrcombo + (size_t)rel * 256 + c);
            H8 uhrp = *(const H8*)(hrcombo + (size_t)rel * 256 + 128 + c);
            H8 uqrp = *(const H8*)(qrb + (size_t)ridx * 128 + c);
            while (true) {
                const int en = e + 4;
                const bool more = en < e1;
                H8 nhw, nhsp, nrw, nhrp, nqrp;
                if (more) {   // prefetch next batch while current computes
                    const unsigned nrec = sorted[en];
                    const int ns = nrec & 0xFFFF, nr = (nrec >> 16) & 0x1FF, nq = nrec >> 25;
                    nhw  = *(const H8*)(combo + (size_t)ns * 256 + c);
                    nhsp = *(const H8*)(combo + (size_t)ns * 256 + 128 + c);
                    nrw  = *(const H8*)(hrcombo + (size_t)nr * 256 + c);
                    nhrp = *(const H8*)(hrcombo + (size_t)nr * 256 + 128 + c);
                    nqrp = *(const H8*)(qrb + (size_t)nq * 128 + c);
                }
                __half2 d2 = zero2;
                #pragma unroll
                for (int j = 0; j < 4; ++j) {
                    const __half2 p = hmax2(__hadd2(__hadd2(uhsp.h[j], uhrp.h[j]), uqrp.h[j]), zero2);
                    d2 = __hfma2(p, wah[j], d2);
                }
                float part = __low2float(d2) + __high2float(d2);
                #pragma unroll
                for (int off = 8; off > 0; off >>= 1) part += __shfl_xor(part, off, 64);
                const float alpha = 1.f / (1.f + __expf(-part));
                #pragma unroll
                for (int j = 0; j < 4; ++j) {
                    const __half2 m = __hadd2(uhw.h[j], urw.h[j]);
                    acc[j * 2]     = fmaf(__low2float(m),  alpha, acc[j * 2]);
                    acc[j * 2 + 1] = fmaf(__high2float(m), alpha, acc[j * 2 + 1]);
                }
                if (!more) break;
                e = en;
                uhw = nhw; uhsp = nhsp; urw = nrw; uhrp = nhrp; uqrp = nqrp;
            }
        }
        #pragma unroll
        for (int j = 0; j < 8; ++j) {   // combine the 4 edge slots
            acc[j] += __shfl_xor(acc[j], 16, 64);
            acc[j] += __shfl_xor(acc[j], 32, 64);
        }
        if (grp == 0) {
            const float4 o0 = make_float4(fmaxf(acc[0], 0.f), fmaxf(acc[1], 0.f),
                                          fmaxf(acc[2], 0.f), fmaxf(acc[3], 0.f));
            const float4 o1 = make_float4(fmaxf(acc[4], 0.f), fmaxf(acc[5], 0.f),
                                          fmaxf(acc[6], 0.f), fmaxf(acc[7], 0.f));
            *(float4*)(out + (size_t)n * D + c)     = o0;
            *(float4*)(out + (size_t)n * D + c + 4) = o1;
        }
    }
}

extern "C" void kernel_launch(void* const* d_in, const int* in_sizes, int n_in,
                              void* d_out, int out_size, void* d_ws, size_t ws_size,
                              hipStream_t stream) {
    const int*   q_rel  = (const int*)d_in[0];
    const float* hidden = (const float*)d_in[1];
    const int*   edges  = (const int*)d_in[2];
    const float* rela   = (const float*)d_in[3];
    const float* Ws     = (const float*)d_in[4];
    const float* Wr     = (const float*)d_in[5];
    const float* Wqr_w  = (const float*)d_in[6];
    const float* Wqr_b  = (const float*)d_in[7];
    const float* Wa     = (const float*)d_in[8];
    const float* Wh     = (const float*)d_in[9];

    const int B = in_sizes[0];
    const int N = in_sizes[1] / D;
    const int E = in_sizes[2] / 6;
    const int R = in_sizes[3] / D;

    ushort_t* combo   = (ushort_t*)d_ws;                 // N*256 fp16: hw | hs_proj
    ushort_t* hrcombo = combo + (size_t)N * 256;         // R*256 fp16: rw | hr_proj
    ushort_t* qrb     = hrcombo + (size_t)R * 256;       // B*128 fp16
    ushort_t* Wt4     = qrb + (size_t)B * 128;           // 4*128*128 fp16: Ws,Wr,Wqr,Wh ^T
    int* count  = (int*)(Wt4 + 4 * D * D);               // N
    int* bsum   = count + N;                             // 64
    int* start  = bsum + 64;                             // N+1
    int* cursor = start + N + 1;                         // N
    unsigned* rec    = (unsigned*)(cursor + N);          // E
    int*      obj    = (int*)(rec + E);                  // E
    unsigned* sorted = (unsigned*)(obj + E);             // E

    // CSR build (+ fused weight transpose in blocks 0..3)
    (void)hipMemsetAsync(count, 0, (size_t)N * sizeof(int), stream);
    pack_prep<<<1028, 256, 0, stream>>>(edges, rec, obj, count, E,
                                        Ws, Wr, Wqr_w, Wh, Wt4);
    const int G = (N + 1023) / 1024;
    scan_partial<<<G, 1024, 0, stream>>>(count, bsum, N);
    scan_final<<<G, 1024, 0, stream>>>(count, bsum, start, cursor, N, G);
    scatter2<<<1024, 256, 0, stream>>>(rec, obj, cursor, sorted, E);

    // all projections in one launch
    const int TB = (N + 63) / 64;
    const int RB = (R + 63) / 64;
    gemm_all<<<TB + RB + 1, 256, 0, stream>>>(hidden, rela, Wt4, Wqr_b, q_rel,
                                              combo, hrcombo, qrb, N, R, B, TB, RB);

    // final: gather-aggregate + relu -> d_out
    agg_v8<<<2048, 256, 0, stream>>>(sorted, start, (const __half*)combo,
                                     (const __half*)hrcombo, (const __half*)qrb, Wa,
                                     (float*)d_out, N);
}

// Round 11
// 130.673 us; speedup vs baseline: 1.6553x; 1.0884x over previous
//
#include <hip/hip_runtime.h>
#include <hip/hip_fp16.h>
#include <math.h>
#include <stdint.h>

#define D 128
typedef __attribute__((ext_vector_type(8))) _Float16 f16x8;
typedef __attribute__((ext_vector_type(4))) float f32x4;
typedef unsigned short ushort_t;

__device__ inline unsigned pack_f16(float a, float b) {
    __half2 h = __floats2half2_rn(a, b);
    return __builtin_bit_cast(unsigned, h);
}
__device__ inline ushort_t f16_of(float f) {
    __half h = __float2half_rn(f);
    return __builtin_bit_cast(ushort_t, h);
}
__device__ inline __half2 hmax2(__half2 a, __half2 b) {
    unsigned ua = __builtin_bit_cast(unsigned, a);
    unsigned ub = __builtin_bit_cast(unsigned, b);
    unsigned r;
    asm("v_pk_max_f16 %0, %1, %2" : "=v"(r) : "v"(ua), "v"(ub));
    return __builtin_bit_cast(__half2, r);
}

struct __align__(16) H8 { __half2 h[4]; };

// ------------- fused: W->W^T fp16 prep (blocks 0..3) + edge pack/hist (blocks 4+) -------
// rec = sub:16 | rel:9 | r_idx:7
__global__ void pack_prep(const int* __restrict__ edges, unsigned* __restrict__ rec,
                          int* __restrict__ obj, int* __restrict__ count, int E,
                          const float* __restrict__ W0, const float* __restrict__ W1,
                          const float* __restrict__ W2, const float* __restrict__ W3,
                          ushort_t* __restrict__ Wt4) {
    __shared__ ushort_t sT[D * D];
    const int t = threadIdx.x;
    if (blockIdx.x < 4) {   // transpose+convert one weight matrix
        const float* src = blockIdx.x == 0 ? W0 : blockIdx.x == 1 ? W1 : blockIdx.x == 2 ? W2 : W3;
        ushort_t* dst = Wt4 + (size_t)blockIdx.x * (D * D);
        for (int i = t; i < D * D; i += 256) {
            const int k = i >> 7, col = i & 127;
            sT[col * D + k] = f16_of(src[i]);
        }
        __syncthreads();
        const uint4* s8 = (const uint4*)sT;
        uint4* d8 = (uint4*)dst;
        for (int i = t; i < D * D / 8; i += 256) d8[i] = s8[i];
    } else {                // pack edges + histogram
        const int i0 = (blockIdx.x - 4) * blockDim.x + t;
        const int stride = (gridDim.x - 4) * blockDim.x;
        const uint2* e2 = (const uint2*)edges;
        for (int e = i0; e < E; e += stride) {
            const unsigned r_idx = e2[e * 3 + 0].x;
            const unsigned rel   = e2[e * 3 + 1].x;
            const uint2 so       = e2[e * 3 + 2];     // .x=sub .y=obj
            rec[e] = so.x | (rel << 16) | (r_idx << 25);
            obj[e] = (int)so.y;
            atomicAdd(&count[so.y], 1);
        }
    }
}

// ---------------- 2-phase exclusive scan ----------------
__global__ void scan_partial(const int* __restrict__ count, int* __restrict__ bsum, int M) {
    __shared__ int wsum[16];
    const int t = threadIdx.x, lane = t & 63, w = t >> 6;
    const int i = blockIdx.x * 1024 + t;
    int v = (i < M) ? count[i] : 0;
    #pragma unroll
    for (int off = 32; off > 0; off >>= 1) v += __shfl_xor(v, off, 64);
    if (lane == 0) wsum[w] = v;
    __syncthreads();
    if (w == 0) {
        int s = (lane < 16) ? wsum[lane] : 0;
        #pragma unroll
        for (int off = 8; off > 0; off >>= 1) s += __shfl_xor(s, off, 16);
        if (lane == 0) bsum[blockIdx.x] = s;
    }
}

__global__ void scan_final(const int* __restrict__ count, const int* __restrict__ bsum,
                           int* __restrict__ start, int* __restrict__ cursor, int M, int G) {
    __shared__ int wsum[16];
    __shared__ int sboff;
    const int t = threadIdx.x, lane = t & 63, w = t >> 6;
    const int i = blockIdx.x * 1024 + t;
    const int v = (i < M) ? count[i] : 0;
    if (w == 0) {
        int bv = (lane < G) ? bsum[lane] : 0;
        int bx = bv;
        #pragma unroll
        for (int off = 1; off < 64; off <<= 1) {
            int y = __shfl_up(bx, off, 64);
            if (lane >= off) bx += y;
        }
        if (lane == (blockIdx.x & 63)) sboff = bx - bv;
    }
    int x = v;
    #pragma unroll
    for (int off = 1; off < 64; off <<= 1) {
        int y = __shfl_up(x, off, 64);
        if (lane >= off) x += y;
    }
    if (lane == 63) wsum[w] = x;
    __syncthreads();
    if (w == 0) {
        int s = (lane < 16) ? wsum[lane] : 0;
        int xs = s;
        #pragma unroll
        for (int off = 1; off < 16; off <<= 1) {
            int y = __shfl_up(xs, off, 64);
            if (lane >= off) xs += y;
        }
        if (lane < 16) wsum[lane] = xs - s;
    }
    __syncthreads();
    const int excl = x - v + wsum[w] + sboff;
    if (i < M) {
        start[i] = excl;
        cursor[i] = excl;
        if (i == M - 1) start[M] = excl + v;
    }
}

// ---------------- scatter packed recs into CSR order ----------------
__global__ void scatter2(const unsigned* __restrict__ rec, const int* __restrict__ obj,
                         int* __restrict__ cursor, unsigned* __restrict__ sorted, int E) {
    const int i = blockIdx.x * blockDim.x + threadIdx.x;
    const int stride = gridDim.x * blockDim.x;
    for (int e = i; e < E; e += stride) {
        const int pos = atomicAdd(&cursor[obj[e]], 1);
        sorted[pos] = rec[e];
    }
}

// ---- LDS staging helpers (XOR-swizzled layout, 256B rows) ----
__device__ inline void stage_w(ushort_t* sW, const ushort_t* Wt, int t) {
    const uint4* src = (const uint4*)Wt;
    for (int s = t; s < 2048; s += 256) {
        const int col = s >> 4;
        const int off = (s & 15) * 16;
        *(uint4*)((char*)sW + col * 256 + (off ^ ((col & 7) << 4))) = src[s];
    }
}
__device__ inline void stage_x(ushort_t* sX, const float* X, const int* rowidx,
                               int r0, int M, int t) {
    const int row = t >> 2, q = t & 3;
    const int gr = r0 + row;
    if (gr < M) {
        const int src = rowidx ? rowidx[gr] : gr;
        const float* xp = X + (size_t)src * D + q * 32;
        #pragma unroll
        for (int s = 0; s < 4; ++s) {
            const float4 v0 = *(const float4*)(xp + s * 8);
            const float4 v1 = *(const float4*)(xp + s * 8 + 4);
            uint4 pk;
            pk.x = pack_f16(v0.x, v0.y); pk.y = pack_f16(v0.z, v0.w);
            pk.z = pack_f16(v1.x, v1.y); pk.w = pack_f16(v1.z, v1.w);
            const int off = q * 64 + s * 16;
            *(uint4*)((char*)sX + row * 256 + (off ^ ((row & 7) << 4))) = pk;
        }
    }
}

// ---------------- all projections in one launch ----------------
// blocks [0,TB):       combo   = [hidden@Wh | hidden@Ws]
// blocks [TB,TB+RB):   hrcombo = [rela@Wh   | rela@Wr]
// block  TB+RB:        qrb     = rela[q_rel]@Wqr + bias
__global__ __launch_bounds__(256, 2)
void gemm_all(const float* __restrict__ hidden, const float* __restrict__ rela,
              const ushort_t* __restrict__ Wt4, const float* __restrict__ bias,
              const int* __restrict__ q_rel,
              ushort_t* __restrict__ combo, ushort_t* __restrict__ hrcombo,
              ushort_t* __restrict__ qrb, int N, int R, int B, int TB, int RB) {
    __shared__ ushort_t sWA[D * D];  // 32 KB
    __shared__ ushort_t sWB[D * D];  // 32 KB
    __shared__ ushort_t sX[64 * D];  // 16 KB
    const int t = threadIdx.x;
    const int wave = t >> 6, lane = t & 63;
    const int l15 = lane & 15, lg = lane >> 4;
    const int bid = blockIdx.x;

    const bool qpath = (bid == TB + RB);
    const float* X   = (bid < TB) ? hidden : rela;
    const int    M   = (bid < TB) ? N : (qpath ? B : R);
    const int    r0  = (bid < TB) ? bid * 64 : (qpath ? 0 : (bid - TB) * 64);
    ushort_t*    Y   = (bid < TB) ? combo : (qpath ? qrb : hrcombo);

    if (!qpath) {
        stage_w(sWA, Wt4 + 3 * D * D, t);                         // Wh^T
        stage_w(sWB, (bid < TB) ? Wt4 : (Wt4 + D * D), t);        // Ws^T or Wr^T
        stage_x(sX, X, nullptr, r0, M, t);
        __syncthreads();
        f32x4 accA[8], accB[8];
        #pragma unroll
        for (int ct = 0; ct < 8; ++ct) {
            accA[ct] = (f32x4){0.f, 0.f, 0.f, 0.f};
            accB[ct] = (f32x4){0.f, 0.f, 0.f, 0.f};
        }
        #pragma unroll
        for (int kc = 0; kc < 4; ++kc) {
            const int koff = kc * 64 + lg * 16;
            const int arow = wave * 16 + l15;
            const f16x8 afrag = *(const f16x8*)((char*)sX + arow * 256 + (koff ^ ((arow & 7) << 4)));
            #pragma unroll
            for (int ct = 0; ct < 8; ++ct) {
                const int col = ct * 16 + l15;
                const int sw = koff ^ ((col & 7) << 4);
                const f16x8 bfA = *(const f16x8*)((char*)sWA + col * 256 + sw);
                const f16x8 bfB = *(const f16x8*)((char*)sWB + col * 256 + sw);
                accA[ct] = __builtin_amdgcn_mfma_f32_16x16x32_f16(afrag, bfA, accA[ct], 0, 0, 0);
                accB[ct] = __builtin_amdgcn_mfma_f32_16x16x32_f16(afrag, bfB, accB[ct], 0, 0, 0);
            }
        }
        #pragma unroll
        for (int q2 = 0; q2 < 4; ++q2) {
            const int gr2 = r0 + wave * 16 + lg * 4 + q2;
            if (gr2 < M) {
                #pragma unroll
                for (int ct = 0; ct < 8; ++ct) {
                    const int col = ct * 16 + l15;
                    Y[(size_t)gr2 * 256 + col]       = f16_of(accA[ct][q2]);   // @Wh
                    Y[(size_t)gr2 * 256 + 128 + col] = f16_of(accB[ct][q2]);   // @Ws / @Wr
                }
            }
        }
    } else {
        stage_w(sWA, Wt4 + 2 * D * D, t);                         // Wqr^T
        stage_x(sX, X, q_rel, 0, M, t);
        __syncthreads();
        f32x4 acc[8];
        #pragma unroll
        for (int ct = 0; ct < 8; ++ct) acc[ct] = (f32x4){0.f, 0.f, 0.f, 0.f};
        #pragma unroll
        for (int kc = 0; kc < 4; ++kc) {
            const int koff = kc * 64 + lg * 16;
            const int arow = wave * 16 + l15;
            const f16x8 afrag = *(const f16x8*)((char*)sX + arow * 256 + (koff ^ ((arow & 7) << 4)));
            #pragma unroll
            for (int ct = 0; ct < 8; ++ct) {
                const int col = ct * 16 + l15;
                const f16x8 bf = *(const f16x8*)((char*)sWA + col * 256 + (koff ^ ((col & 7) << 4)));
                acc[ct] = __builtin_amdgcn_mfma_f32_16x16x32_f16(afrag, bf, acc[ct], 0, 0, 0);
            }
        }
        #pragma unroll
        for (int q2 = 0; q2 < 4; ++q2) {
            const int gr2 = wave * 16 + lg * 4 + q2;
            if (gr2 < M) {
                #pragma unroll
                for (int ct = 0; ct < 8; ++ct) {
                    const int col = ct * 16 + l15;
                    Y[(size_t)gr2 * 128 + col] = f16_of(acc[ct][q2] + bias[col]);
                }
            }
        }
    }
}

// ------- per-node aggregation: out = relu(sum a*(hw+rw)) f32; rec-only prefetch -------
__global__ void agg_v9(const unsigned* __restrict__ sorted, const int* __restrict__ start,
                       const __half* __restrict__ combo,    // [N][256]: hw | hs_proj
                       const __half* __restrict__ hrcombo,  // [R][256]: rw | hr_proj
                       const __half* __restrict__ qrb,      // [B][128]: qr_proj
                       const float* __restrict__ Wa,
                       float* __restrict__ out, int N) {
    const int gtid = blockIdx.x * blockDim.x + threadIdx.x;
    const int wave = gtid >> 6;
    const int lane = threadIdx.x & 63;
    const int nwaves = (gridDim.x * blockDim.x) >> 6;
    const int grp = lane >> 4;        // 0..3 : edge slot within wave
    const int sl  = lane & 15;        // 0..15
    const int c   = sl * 8;           // 8 cols per lane
    __half2 wah[4];
    {
        const float4 w0 = *(const float4*)(Wa + c);
        const float4 w1 = *(const float4*)(Wa + c + 4);
        wah[0] = __floats2half2_rn(w0.x, w0.y);
        wah[1] = __floats2half2_rn(w0.z, w0.w);
        wah[2] = __floats2half2_rn(w1.x, w1.y);
        wah[3] = __floats2half2_rn(w1.z, w1.w);
    }
    const __half2 zero2 = __floats2half2_rn(0.f, 0.f);
    for (int n = wave; n < N; n += nwaves) {
        const int e0 = start[n], e1 = start[n + 1];
        float acc[8] = {0.f, 0.f, 0.f, 0.f, 0.f, 0.f, 0.f, 0.f};
        int e = e0 + grp;
        unsigned nrec = (e < e1) ? sorted[e] : 0u;
        for (; e < e1; e += 4) {
            const unsigned rec = nrec;
            if (e + 4 < e1) nrec = sorted[e + 4];   // only the index word is prefetched
            const int sub  = rec & 0xFFFF;
            const int rel  = (rec >> 16) & 0x1FF;
            const int ridx = rec >> 25;
            const H8 uhw  = *(const H8*)(combo + (size_t)sub * 256 + c);
            const H8 uhsp = *(const H8*)(combo + (size_t)sub * 256 + 128 + c);
            const H8 urw  = *(const H8*)(hrcombo + (size_t)rel * 256 + c);
            const H8 uhrp = *(const H8*)(hrcombo + (size_t)rel * 256 + 128 + c);
            const H8 uqrp = *(const H8*)(qrb + (size_t)ridx * 128 + c);
            __half2 d2 = zero2;
            #pragma unroll
            for (int j = 0; j < 4; ++j) {
                const __half2 p = hmax2(__hadd2(__hadd2(uhsp.h[j], uhrp.h[j]), uqrp.h[j]), zero2);
                d2 = __hfma2(p, wah[j], d2);
            }
            float part = __low2float(d2) + __high2float(d2);
            #pragma unroll
            for (int off = 8; off > 0; off >>= 1) part += __shfl_xor(part, off, 64);
            const float alpha = 1.f / (1.f + __expf(-part));
            #pragma unroll
            for (int j = 0; j < 4; ++j) {
                const __half2 m = __hadd2(uhw.h[j], urw.h[j]);
                acc[j * 2]     = fmaf(__low2float(m),  alpha, acc[j * 2]);
                acc[j * 2 + 1] = fmaf(__high2float(m), alpha, acc[j * 2 + 1]);
            }
        }
        #pragma unroll
        for (int j = 0; j < 8; ++j) {   // combine the 4 edge slots
            acc[j] += __shfl_xor(acc[j], 16, 64);
            acc[j] += __shfl_xor(acc[j], 32, 64);
        }
        if (grp == 0) {
            const float4 o0 = make_float4(fmaxf(acc[0], 0.f), fmaxf(acc[1], 0.f),
                                          fmaxf(acc[2], 0.f), fmaxf(acc[3], 0.f));
            const float4 o1 = make_float4(fmaxf(acc[4], 0.f), fmaxf(acc[5], 0.f),
                                          fmaxf(acc[6], 0.f), fmaxf(acc[7], 0.f));
            *(float4*)(out + (size_t)n * D + c)     = o0;
            *(float4*)(out + (size_t)n * D + c + 4) = o1;
        }
    }
}

extern "C" void kernel_launch(void* const* d_in, const int* in_sizes, int n_in,
                              void* d_out, int out_size, void* d_ws, size_t ws_size,
                              hipStream_t stream) {
    const int*   q_rel  = (const int*)d_in[0];
    const float* hidden = (const float*)d_in[1];
    const int*   edges  = (const int*)d_in[2];
    const float* rela   = (const float*)d_in[3];
    const float* Ws     = (const float*)d_in[4];
    const float* Wr     = (const float*)d_in[5];
    const float* Wqr_w  = (const float*)d_in[6];
    const float* Wqr_b  = (const float*)d_in[7];
    const float* Wa     = (const float*)d_in[8];
    const float* Wh     = (const float*)d_in[9];

    const int B = in_sizes[0];
    const int N = in_sizes[1] / D;
    const int E = in_sizes[2] / 6;
    const int R = in_sizes[3] / D;

    ushort_t* combo   = (ushort_t*)d_ws;                 // N*256 fp16: hw | hs_proj
    ushort_t* hrcombo = combo + (size_t)N * 256;         // R*256 fp16: rw | hr_proj
    ushort_t* qrb     = hrcombo + (size_t)R * 256;       // B*128 fp16
    ushort_t* Wt4     = qrb + (size_t)B * 128;           // 4*128*128 fp16: Ws,Wr,Wqr,Wh ^T
    int* count  = (int*)(Wt4 + 4 * D * D);               // N
    int* bsum   = count + N;                             // 64
    int* start  = bsum + 64;                             // N+1
    int* cursor = start + N + 1;                         // N
    unsigned* rec    = (unsigned*)(cursor + N);          // E
    int*      obj    = (int*)(rec + E);                  // E
    unsigned* sorted = (unsigned*)(obj + E);             // E

    // CSR build (+ fused weight transpose in blocks 0..3)
    (void)hipMemsetAsync(count, 0, (size_t)N * sizeof(int), stream);
    pack_prep<<<1028, 256, 0, stream>>>(edges, rec, obj, count, E,
                                        Ws, Wr, Wqr_w, Wh, Wt4);
    const int G = (N + 1023) / 1024;
    scan_partial<<<G, 1024, 0, stream>>>(count, bsum, N);
    scan_final<<<G, 1024, 0, stream>>>(count, bsum, start, cursor, N, G);
    scatter2<<<1024, 256, 0, stream>>>(rec, obj, cursor, sorted, E);

    // all projections in one launch
    const int TB = (N + 63) / 64;
    const int RB = (R + 63) / 64;
    gemm_all<<<TB + RB + 1, 256, 0, stream>>>(hidden, rela, Wt4, Wqr_b, q_rel,
                                              combo, hrcombo, qrb, N, R, B, TB, RB);

    // final: gather-aggregate + relu -> d_out
    agg_v9<<<2048, 256, 0, stream>>>(sorted, start, (const __half*)combo,
                                     (const __half*)hrcombo, (const __half*)qrb, Wa,
                                     (float*)d_out, N);
}